// Round 11
// baseline (195.881 us; speedup 1.0000x reference)
//
#include <hip/hip_runtime.h>

#define Himg 135
#define Wimg 240
#define Bimg 128
#define Cimg 3
#define BCN (Bimg*Cimg)
#define HW (Himg*Wimg)
#define CHW (Cimg*HW)
#define EPSF 1e-10f
#define TOTB (BCN*2*5)

typedef float fvec4 __attribute__((ext_vector_type(4)));
typedef float f2 __attribute__((ext_vector_type(2)));
typedef float f4 __attribute__((ext_vector_type(4)));
typedef _Float16 hf;
typedef hf h2 __attribute__((ext_vector_type(2)));
typedef hf h4v __attribute__((ext_vector_type(4)));
typedef hf h8 __attribute__((ext_vector_type(8)));

// R25: spill bisection. R24 falsified "AddrSet caused the spill" (removed
// it; WRITE still 11MB, dispatch 106). Remaining suspects from the R22->R23
// delta: affine Ar address vs batched-trans accumulators. This round:
// base = VERBATIM R22 (93us clean: per-call rowL+XOR in htile), plus ONLY
//  1) batched trans: den log10 once per JOB (denJ), num div+log once per
//     vtile PAIR (pT/pB) -- the piece with measured VALU reduction
//     (58->53.5 us-equiv in R23/R24);
//  2) always_inline on htile/vtile lambdas (defensive: non-inlined lambda
//     with by-ref captures would materialize frames on scratch).
// A/B read: WRITE~480KB -> affine addr was the trigger, bank the win;
// WRITE~11MB -> accumulator lifetimes are the trigger, revert to R22.
// Keeps: barrier-free private-column structure, pair-unrolled pipeline,
// full/edge vtile split, m3-via-algebra, WTAB rodata weights, setprio,
// relaxed-atomic folded finalize (no L2-flush fences).
// LDS (hf units): Ar [77][64] @0 (XOR swz (row&7)<<3), Ap @4928,
// HtW 4 x [16 ln][5 ch][2 slots x 16 rows] @9856 (XOR swz (ln&7)<<3),
// sred @20096. Total 40240 B -> 4 blocks/CU.
#define RSTG 77
#define ASTR 64
#define APOFF 4928
#define HT0   9856
#define HTWSZ 2560
#define SREDO 20096
#define LDSB  40240

#define ALWAYS_INLINE __attribute__((always_inline))

__device__ __forceinline__ h2 pkrtz(float a, float b) {
  return __builtin_bit_cast(h2, __builtin_amdgcn_cvt_pkrtz(a, b));
}
__device__ __forceinline__ h4v pkrtz4(float a, float b, float c, float d) {
  h2 lo = pkrtz(a, b), hi = pkrtz(c, d);
  return (h4v){lo[0], lo[1], hi[0], hi[1]};
}
__device__ __forceinline__ float aload(const float* p) {
  return __hip_atomic_load(p, __ATOMIC_RELAXED, __HIP_MEMORY_SCOPE_AGENT);
}

constexpr double cexp(double x) {
  double s = 1.0, t = 1.0;
  for (int i = 1; i < 48; ++i) { t *= x / (double)i; s += t; }
  return s;
}
template<int N>
struct GaussW {
  float inv, rsum;
  constexpr GaussW() : inv(0), rsum(0) {
    const float sig = (float)N / 5.0f;
    inv = 1.0f / (2.0f * sig * sig);
    float ssum = 0.f;
    for (int i = 0; i < N; ++i) {
      float d = (float)(i - N / 2);
      ssum += (float)cexp((double)(-(d * d) * inv));
    }
    rsum = 1.0f / ssum;
  }
};

// Compile-time Toeplitz weight fragments: w[lane][j] for k=quad*8+j,
// di=k-ln (tap d -> grid d-N/2). Valid taps only (0<=di<N), else 0.
struct alignas(16) W8 { hf v[8]; };
template<int N>
struct WTabS {
  W8 w[64];
  constexpr WTabS() : w{} {
    constexpr GaussW<N> GW{};
    for (int l = 0; l < 64; ++l) {
      const int ln = l & 15, quad = l >> 4;
      for (int j = 0; j < 8; ++j) {
        const int di = quad * 8 + j - ln;
        const float fd = (float)(di - N / 2);
        float val = 0.f;
        if (di >= 0 && di < N)
          val = (float)cexp((double)(-(fd * fd) * GW.inv)) * GW.rsum;
        w[l].v[j] = (hf)val;
      }
    }
  }
};
template<int N> __device__ constexpr WTabS<N> WTAB{};

// ws layout (floats): [0,384) num, [384,768) den, [768,896) per-image dots,
// [896] block-done counter (u32).

template<int N>
__device__ __forceinline__ void job_col(
    int ct, int chunk, int band, const hf* __restrict__ Ar,
    const hf* __restrict__ Ap, hf* __restrict__ HtW,
    int ln, int quad, int hb0, int hb1, int vb0, int vb1,
    float& numAcc, float& denAcc)
{
  constexpr int OW  = Wimg - N + 1;
  constexpr int OV  = Himg - N + 1;
  constexpr int OV0 = (OV + 1) / 2;
  constexpr int TIL = (OV0 + 15) / 16;   // V tiles (chunk-invariant)

  const int OVc  = chunk ? (OV - OV0) : OV0;
  const int hoff = chunk ? (OV0 - 58) : 0;   // staged-local row of tap 0
  const f4 zf = {0.f, 0.f, 0.f, 0.f};

  // One 16B rodata load replaces the 8x exp/select/cvt rebuild.
  const h8 wfrag = *(const h8*)(WTAB<N>.w + (quad * 16 + ln));

  const int swz  = (ln & 7) << 3;            // Ht XOR swizzle (16B units)
  const int ocol = band * 48 + ct * 16 + ln;
  const bool colv = ocol < OW;
  const int nFull = colv ? (OVc >> 4) : 0;

  auto htile = [&](int t, int hb) ALWAYS_INLINE {   // hb literal-selected
    int rowL = hoff + t * 16 + ln;
    if (rowL > RSTG - 1) rowL = RSTG - 1;    // finite clamp; masked by inb
    const int ao = (rowL * ASTR + ct * 16 + quad * 8) ^ ((rowL & 7) << 3);
    h8 ra = *(const h8*)(Ar + ao);
    h8 pa = *(const h8*)(Ap + ao);
    h8 rsq = ra * ra, psq = pa * pa, rp = ra * pa;
    __builtin_amdgcn_s_setprio(1);
    f4 d0 = __builtin_amdgcn_mfma_f32_16x16x32_f16(ra,  wfrag, zf, 0, 0, 0);
    f4 d1 = __builtin_amdgcn_mfma_f32_16x16x32_f16(pa,  wfrag, zf, 0, 0, 0);
    f4 d2 = __builtin_amdgcn_mfma_f32_16x16x32_f16(rsq, wfrag, zf, 0, 0, 0);
    f4 d3 = __builtin_amdgcn_mfma_f32_16x16x32_f16(psq, wfrag, zf, 0, 0, 0);
    f4 d4 = __builtin_amdgcn_mfma_f32_16x16x32_f16(rp,  wfrag, zf, 0, 0, 0);
    __builtin_amdgcn_s_setprio(0);
    *(h4v*)(HtW + ((hb + 0 * 32) ^ swz)) = pkrtz4(d0[0], d0[1], d0[2], d0[3]);
    *(h4v*)(HtW + ((hb + 1 * 32) ^ swz)) = pkrtz4(d1[0], d1[1], d1[2], d1[3]);
    *(h4v*)(HtW + ((hb + 2 * 32) ^ swz)) = pkrtz4(d2[0], d2[1], d2[2], d2[3]);
    *(h4v*)(HtW + ((hb + 3 * 32) ^ swz)) = pkrtz4(d3[0], d3[1], d3[2], d3[3]);
    *(h4v*)(HtW + ((hb + 4 * 32) ^ swz)) = pkrtz4(d4[0], d4[1], d4[2], d4[3]);
  };

  auto vtile = [&](int v, int rbase, bool full,
                   float& pT, float& pB, float& denJ) ALWAYS_INLINE {
    const int j0 = v * 16;
    f4 C[5];
    __builtin_amdgcn_s_setprio(1);
    #pragma unroll
    for (int c = 0; c < 5; ++c) {
      h8 bf = *(const h8*)(HtW + ((rbase + c * 32) ^ swz));
      C[c] = __builtin_amdgcn_mfma_f32_16x16x32_f16(wfrag, bf, zf, 0, 0, 0);
    }
    __builtin_amdgcn_s_setprio(0);
    // m3 via algebra: t1 = fmax(sGP,0)^2 -> sGP<=0 => T==D => factor 1.
    const f2 z2 = {0.f, 0.f};
    if (full) {
      #pragma unroll
      for (int pr2 = 0; pr2 < 2; ++pr2) {
        f2 mu1 = {C[0][2 * pr2], C[0][2 * pr2 + 1]};
        f2 mu2 = {C[1][2 * pr2], C[1][2 * pr2 + 1]};
        f2 m2c = {C[2][2 * pr2], C[2][2 * pr2 + 1]};
        f2 m3c = {C[3][2 * pr2], C[3][2 * pr2 + 1]};
        f2 m4c = {C[4][2 * pr2], C[4][2 * pr2 + 1]};
        f2 sGT = __builtin_elementwise_max(m2c - mu1 * mu1, z2);
        f2 sP  = __builtin_elementwise_max(m3c - mu2 * mu2, z2);
        f2 sGPc= __builtin_elementwise_max(m4c - mu1 * mu2, z2);
        f2 A   = sGT + EPSF;
        f2 t1  = sGPc * sGPc;
        f2 D   = A * __builtin_elementwise_fma(sP + 2.f, A, -t1);
        f2 T   = D + t1 * sGT;
        f2 dn2 = __builtin_elementwise_fma(sGT, (f2){0.5f, 0.5f}, (f2){1.f, 1.f});
        f2 mn  = __builtin_elementwise_min(sGT, sP);
        denJ *= dn2[0] * dn2[1];
        #pragma unroll
        for (int e = 0; e < 2; ++e) {
          const bool valid = mn[e] >= EPSF;
          pT *= valid ? T[e] : 1.f;
          pB *= valid ? D[e] : 1.f;
        }
      }
    } else {
      #pragma unroll
      for (int pr2 = 0; pr2 < 2; ++pr2) {
        f2 mu1 = {C[0][2 * pr2], C[0][2 * pr2 + 1]};
        f2 mu2 = {C[1][2 * pr2], C[1][2 * pr2 + 1]};
        f2 m2c = {C[2][2 * pr2], C[2][2 * pr2 + 1]};
        f2 m3c = {C[3][2 * pr2], C[3][2 * pr2 + 1]};
        f2 m4c = {C[4][2 * pr2], C[4][2 * pr2 + 1]};
        f2 sGT = __builtin_elementwise_max(m2c - mu1 * mu1, z2);
        f2 sP  = __builtin_elementwise_max(m3c - mu2 * mu2, z2);
        f2 sGPc= __builtin_elementwise_max(m4c - mu1 * mu2, z2);
        f2 A   = sGT + EPSF;
        f2 t1  = sGPc * sGPc;
        f2 D   = A * __builtin_elementwise_fma(sP + 2.f, A, -t1);
        f2 T   = D + t1 * sGT;
        f2 dn2 = __builtin_elementwise_fma(sGT, (f2){0.5f, 0.5f}, (f2){1.f, 1.f});
        f2 mn  = __builtin_elementwise_min(sGT, sP);
        #pragma unroll
        for (int e = 0; e < 2; ++e) {
          const int orow = j0 + quad * 4 + pr2 * 2 + e;
          const bool inb = (orow < OVc) && colv;
          const bool valid = inb && (mn[e] >= EPSF);
          pT *= valid ? T[e] : 1.f;
          pB *= valid ? D[e] : 1.f;
          denJ *= inb ? dn2[e] : 1.f;
        }
      }
    }
  };

  // software pipeline, pair-unrolled; num div+log per PAIR, den log per JOB.
  float denJ = 1.f;
  htile(0, hb0);
  int v = 0;
  #pragma unroll 1
  for (; v + 1 < TIL; v += 2) {
    float pT = 1.f, pB = 1.f;
    htile(v + 1, hb1);   // slot 1
    vtile(v, vb0, v < nFull, pT, pB, denJ);
    htile(v + 2, hb0);   // slot 0
    vtile(v + 1, vb1, (v + 1) < nFull, pT, pB, denJ);
    numAcc += __log10f(__fdividef(pT, pB));
  }
  if constexpr (TIL & 1) {       // s5/s3 tail (TIL=5)
    float pT = 1.f, pB = 1.f;
    htile(TIL, hb1);     // t=TIL, slot 1
    vtile(TIL - 1, vb0, (TIL - 1) < nFull, pT, pB, denJ);
    numAcc += __log10f(__fdividef(pT, pB));
  }
  denAcc += __log10f(denJ);
}

// grid: 3840 blocks = 384 bc x 2 chunks x 5 bands, all identical type
__global__ __launch_bounds__(256, 4) void vif_fat_kernel(
    const float* __restrict__ recons, const float* __restrict__ xim,
    const float* __restrict__ Wl, float* __restrict__ ws,
    float* __restrict__ out)
{
  extern __shared__ hf lds[];
  hf* Ar = lds;
  hf* Ap = lds + APOFF;
  float* sred = (float*)(lds + SREDO);

  const int b     = blockIdx.x;
  const int band  = b % 5;
  const int rest  = b / 5;
  const int chunk = rest & 1;
  const int bc    = rest >> 1;
  const int img   = bc / 3;
  const int tid   = threadIdx.x;
  const int lane  = tid & 63;
  const int ln    = lane & 15;
  const int quad  = lane >> 4;
  const int wave  = tid >> 6;
  const int r0s   = chunk ? 58 : 0;          // first staged row

  hf* HtW = lds + HT0 + wave * HTWSZ;        // private per-wave Ht ring

  // Hoisted ring-slot bases (job/scale-invariant, 4 scalars only).
  const int qh   = quad >> 1;
  const int hq8  = 8 * (quad & 1);
  const int hb0  = ln * 160 + quad * 4;             // H slot 0
  const int hb1  = hb0 + 16;                        // H slot 1
  const int vb0  = ln * 160 + qh * 16 + hq8;        // V parity 0
  const int vb1  = ln * 160 + (qh ^ 1) * 16 + hq8;  // V parity 1

  const float* rb = recons + bc * HW;
  const float* pb = xim + bc * HW;
  const float* wb = Wl + (bc % 3) * HW;

  // ---- Stage 77x64 f16 strip (XOR-swizzled) + fused dot ----
  float dotAcc = 0.f;
  #pragma unroll
  for (int i = 0; i < 3; ++i) {
    const int it = tid + i * 256;
    if (it < RSTG * 8) {
      const int row = it >> 3;
      const int c8  = it & 7;
      const int grow = r0s + row;
      int gcol = band * 48 + c8 * 8;
      if (gcol > Wimg - 8) gcol = Wimg - 8;    // finite clamp (halo cols only)
      const int idx = grow * Wimg + gcol;
      fvec4 r0 = *(const fvec4*)(rb + idx);
      fvec4 r1 = *(const fvec4*)(rb + idx + 4);
      fvec4 p0 = *(const fvec4*)(pb + idx);
      fvec4 p1 = *(const fvec4*)(pb + idx + 4);
      h2 a0 = pkrtz(r0[0], r0[1]), a1 = pkrtz(r0[2], r0[3]);
      h2 a2 = pkrtz(r1[0], r1[1]), a3 = pkrtz(r1[2], r1[3]);
      h2 b0 = pkrtz(p0[0], p0[1]), b1 = pkrtz(p0[2], p0[3]);
      h2 b2 = pkrtz(p1[0], p1[1]), b3 = pkrtz(p1[2], p1[3]);
      const int wo = (row * ASTR + c8 * 8) ^ ((row & 7) << 3);
      *(h8*)(Ar + wo) =
          (h8){a0[0], a0[1], a1[0], a1[1], a2[0], a2[1], a3[0], a3[1]};
      *(h8*)(Ap + wo) =
          (h8){b0[0], b0[1], b1[0], b1[1], b2[0], b2[1], b3[0], b3[1]};
      const bool rowOwned = chunk ? (grow >= 68) : (grow < 68);
      if (c8 < 6 && rowOwned) {                // owned cols never clamped
        fvec4 w0 = *(const fvec4*)(wb + idx);
        fvec4 w1 = *(const fvec4*)(wb + idx + 4);
        dotAcc += (p0[0]-r0[0])*w0[0] + (p0[1]-r0[1])*w0[1]
                + (p0[2]-r0[2])*w0[2] + (p0[3]-r0[3])*w0[3]
                + (p1[0]-r1[0])*w1[0] + (p1[1]-r1[1])*w1[1]
                + (p1[2]-r1[2])*w1[2] + (p1[3]-r1[3])*w1[3];
      }
    }
  }
  __syncthreads();                            // the ONLY staging barrier

  // ---- 12 (scale,ct) jobs, 3 per wave, barrier-free ----
  // job = wave + jj*4; scale = job/3, ct = job%3.
  // jj loop MUST stay rolled: unrolling would re-create 12 instances.
  float numAcc = 0.f, denAcc = 0.f;
  #pragma unroll 1
  for (int jj = 0; jj < 3; ++jj) {
    const int job  = wave + jj * 4;
    const int sidx = job / 3;
    const int ct   = job - sidx * 3;
    switch (sidx) {
      case 0:  job_col<17>(ct, chunk, band, Ar, Ap, HtW, ln, quad,
                           hb0, hb1, vb0, vb1, numAcc, denAcc); break;
      case 1:  job_col< 9>(ct, chunk, band, Ar, Ap, HtW, ln, quad,
                           hb0, hb1, vb0, vb1, numAcc, denAcc); break;
      case 2:  job_col< 5>(ct, chunk, band, Ar, Ap, HtW, ln, quad,
                           hb0, hb1, vb0, vb1, numAcc, denAcc); break;
      default: job_col< 3>(ct, chunk, band, Ar, Ap, HtW, ln, quad,
                           hb0, hb1, vb0, vb1, numAcc, denAcc); break;
    }
  }

  // ---- block reduction (num, den, dot) ----
  #pragma unroll
  for (int off = 32; off > 0; off >>= 1) {
    numAcc += __shfl_down(numAcc, off);
    denAcc += __shfl_down(denAcc, off);
    dotAcc += __shfl_down(dotAcc, off);
  }
  __syncthreads();
  if (lane == 0) {
    sred[wave] = numAcc; sred[4 + wave] = denAcc; sred[8 + wave] = dotAcc;
  }
  __syncthreads();
  if (tid == 0) {
    atomicAdd(&ws[bc],        sred[0] + sred[1] + sred[2] + sred[3]);
    atomicAdd(&ws[384 + bc],  sred[4] + sred[5] + sred[6] + sred[7]);
    atomicAdd(&ws[768 + img], sred[8] + sred[9] + sred[10] + sred[11]);
    // Cheap release: wait for our own atomic RMWs to be performed at the
    // device coherence point. NO buffer_wbl2/buffer_inv (the R15 killer).
    asm volatile("s_waitcnt vmcnt(0)" ::: "memory");
    unsigned old = atomicAdd((unsigned*)(ws + 896), 1u);
    sred[0] = (old == TOTB - 1) ? 1.f : 0.f;
  }
  __syncthreads();
  if (sred[0] == 0.f) return;                 // not the last block

  // ---- folded finalize: only the dynamically-last block runs this ----
  asm volatile("" ::: "memory");
  float* s1 = (float*)lds;                    // reuse staged LDS
  float* s2 = s1 + 128;
  if (tid < 128) {
    float d = aload(ws + 768 + tid);
    float psq = d * d;
    float vimg = 0.f;
    #pragma unroll
    for (int c = 0; c < 3; ++c) {
      const int bcx = tid * 3 + c;
      vimg += aload(ws + bcx) / aload(ws + 384 + bcx);
    }
    float rl = 1.f - vimg * (1.f / 3.f);
    s1[tid] = psq; s2[tid] = rl;
  }
  __syncthreads();
  for (int off = 64; off > 0; off >>= 1) {
    if (tid < off) { s1[tid] += s1[tid + off]; s2[tid] += s2[tid + off]; }
    __syncthreads();
  }
  if (tid == 0) {
    float pred = s1[0] * (1.f / 128.f);
    float rec  = s2[0] * (1.f / 128.f);
    out[0] = pred + rec;
    out[1] = rec;
    out[2] = pred;
  }
}

extern "C" void kernel_launch(void* const* d_in, const int* in_sizes, int n_in,
                              void* d_out, int out_size, void* d_ws, size_t ws_size,
                              hipStream_t stream) {
  const float* recons = (const float*)d_in[0];
  const float* x      = (const float*)d_in[1];
  const float* Wl     = (const float*)d_in[2];
  float* ws  = (float*)d_ws;
  float* out = (float*)d_out;

  // zero accumulators + done-counter (897 floats; rounded up)
  hipMemsetAsync(d_ws, 0, 904 * sizeof(float), stream);

  vif_fat_kernel<<<TOTB, 256, LDSB, stream>>>(recons, x, Wl, ws, out);
}

// Round 12
// 177.901 us; speedup vs baseline: 1.1011x; 1.1011x over previous
//
#include <hip/hip_runtime.h>

#define Himg 135
#define Wimg 240
#define Bimg 128
#define Cimg 3
#define BCN (Bimg*Cimg)
#define HW (Himg*Wimg)
#define CHW (Cimg*HW)
#define EPSF 1e-10f
#define TOTB (BCN*2*5)

typedef float fvec4 __attribute__((ext_vector_type(4)));
typedef float f2 __attribute__((ext_vector_type(2)));
typedef float f4 __attribute__((ext_vector_type(4)));
typedef _Float16 hf;
typedef hf h2 __attribute__((ext_vector_type(2)));
typedef hf h4v __attribute__((ext_vector_type(4)));
typedef hf h8 __attribute__((ext_vector_type(8)));

// R26 = R22 VERBATIM (session best: 93us dispatch, 178.3us e2e, clean).
// Rationale: R23/R24/R25 bisection proved ANY scalar accumulator living
// across an htile call (denJ/pT/pB) trips a regalloc spill heuristic
// (WRITE 0.48->11MB, +13us) that eats the ~5us-equiv trans saving.
// R22's products are vtile-local -> clean. Banking the best build.
//  - barrier-free private-column structure (1 staging barrier + reduce)
//  - pair-unrolled H/V software pipeline, literal slot bases
//  - full/edge vtile split (bounds gating only on edge tiles)
//  - m3 gate via algebra: t1=fmax(sGP,0)^2 (sGP<=0 -> factor==1)
//  - one-div-per-vtile: prod(1+rn/D) = prod(T)/prod(D)
//  - WTAB rodata Gaussian weights; s_setprio around MFMA clusters
//  - folded finalize, relaxed-atomic protocol (NO __threadfence)
// LDS (hf units): Ar [77][64] @0 (XOR swz (row&7)<<3), Ap @4928,
// HtW 4 x [16 ln][5 ch][2 slots x 16 rows] @9856 (XOR swz (ln&7)<<3),
// sred @20096. Total 40240 B -> 4 blocks/CU.
#define RSTG 77
#define ASTR 64
#define APOFF 4928
#define HT0   9856
#define HTWSZ 2560
#define SREDO 20096
#define LDSB  40240

__device__ __forceinline__ h2 pkrtz(float a, float b) {
  return __builtin_bit_cast(h2, __builtin_amdgcn_cvt_pkrtz(a, b));
}
__device__ __forceinline__ h4v pkrtz4(float a, float b, float c, float d) {
  h2 lo = pkrtz(a, b), hi = pkrtz(c, d);
  return (h4v){lo[0], lo[1], hi[0], hi[1]};
}
__device__ __forceinline__ float aload(const float* p) {
  return __hip_atomic_load(p, __ATOMIC_RELAXED, __HIP_MEMORY_SCOPE_AGENT);
}

constexpr double cexp(double x) {
  double s = 1.0, t = 1.0;
  for (int i = 1; i < 48; ++i) { t *= x / (double)i; s += t; }
  return s;
}
template<int N>
struct GaussW {
  float inv, rsum;
  constexpr GaussW() : inv(0), rsum(0) {
    const float sig = (float)N / 5.0f;
    inv = 1.0f / (2.0f * sig * sig);
    float ssum = 0.f;
    for (int i = 0; i < N; ++i) {
      float d = (float)(i - N / 2);
      ssum += (float)cexp((double)(-(d * d) * inv));
    }
    rsum = 1.0f / ssum;
  }
};

// Compile-time Toeplitz weight fragments: w[lane][j] for k=quad*8+j,
// di=k-ln (tap d -> grid d-N/2). Valid taps only (0<=di<N), else 0.
struct alignas(16) W8 { hf v[8]; };
template<int N>
struct WTabS {
  W8 w[64];
  constexpr WTabS() : w{} {
    constexpr GaussW<N> GW{};
    for (int l = 0; l < 64; ++l) {
      const int ln = l & 15, quad = l >> 4;
      for (int j = 0; j < 8; ++j) {
        const int di = quad * 8 + j - ln;
        const float fd = (float)(di - N / 2);
        float val = 0.f;
        if (di >= 0 && di < N)
          val = (float)cexp((double)(-(fd * fd) * GW.inv)) * GW.rsum;
        w[l].v[j] = (hf)val;
      }
    }
  }
};
template<int N> __device__ constexpr WTabS<N> WTAB{};

// ws layout (floats): [0,384) num, [384,768) den, [768,896) per-image dots,
// [896] block-done counter (u32).

// One (scale N, ct) output column-strip, fully private to one wave.
// H(t, slot): Ar/Ap rows -> 5-ch horizontal conv via MFMA -> ring slot.
// V(v, vb, full): ring slots -> vertical conv via MFMA -> statistics.
template<int N>
__device__ __forceinline__ void job_col(
    int ct, int chunk, int band, const hf* __restrict__ Ar,
    const hf* __restrict__ Ap, hf* __restrict__ HtW,
    int ln, int quad, int hb0, int hb1, int vb0, int vb1,
    float& numAcc, float& denAcc)
{
  constexpr int OW  = Wimg - N + 1;
  constexpr int OV  = Himg - N + 1;
  constexpr int OV0 = (OV + 1) / 2;
  constexpr int TIL = (OV0 + 15) / 16;   // V tiles (chunk-invariant)

  const int OVc  = chunk ? (OV - OV0) : OV0;
  const int hoff = chunk ? (OV0 - 58) : 0;   // staged-local row of tap 0
  const f4 zf = {0.f, 0.f, 0.f, 0.f};

  // One 16B rodata load replaces the 8x exp/select/cvt rebuild.
  const h8 wfrag = *(const h8*)(WTAB<N>.w + (quad * 16 + ln));

  const int swz  = (ln & 7) << 3;            // Ht XOR swizzle (16B units)
  const int ocol = band * 48 + ct * 16 + ln;
  const bool colv = ocol < OW;
  // vtile v is gate-free iff all 16 rows valid AND column valid.
  const int nFull = colv ? (OVc >> 4) : 0;

  auto htile = [&](int t, int hb) {          // hb literal-selected base
    int rowL = hoff + t * 16 + ln;
    if (rowL > RSTG - 1) rowL = RSTG - 1;    // finite clamp; masked by inb
    const int ao = (rowL * ASTR + ct * 16 + quad * 8) ^ ((rowL & 7) << 3);
    h8 ra = *(const h8*)(Ar + ao);
    h8 pa = *(const h8*)(Ap + ao);
    h8 rsq = ra * ra, psq = pa * pa, rp = ra * pa;
    __builtin_amdgcn_s_setprio(1);
    f4 d0 = __builtin_amdgcn_mfma_f32_16x16x32_f16(ra,  wfrag, zf, 0, 0, 0);
    f4 d1 = __builtin_amdgcn_mfma_f32_16x16x32_f16(pa,  wfrag, zf, 0, 0, 0);
    f4 d2 = __builtin_amdgcn_mfma_f32_16x16x32_f16(rsq, wfrag, zf, 0, 0, 0);
    f4 d3 = __builtin_amdgcn_mfma_f32_16x16x32_f16(psq, wfrag, zf, 0, 0, 0);
    f4 d4 = __builtin_amdgcn_mfma_f32_16x16x32_f16(rp,  wfrag, zf, 0, 0, 0);
    __builtin_amdgcn_s_setprio(0);
    *(h4v*)(HtW + ((hb + 0 * 32) ^ swz)) = pkrtz4(d0[0], d0[1], d0[2], d0[3]);
    *(h4v*)(HtW + ((hb + 1 * 32) ^ swz)) = pkrtz4(d1[0], d1[1], d1[2], d1[3]);
    *(h4v*)(HtW + ((hb + 2 * 32) ^ swz)) = pkrtz4(d2[0], d2[1], d2[2], d2[3]);
    *(h4v*)(HtW + ((hb + 3 * 32) ^ swz)) = pkrtz4(d3[0], d3[1], d3[2], d3[3]);
    *(h4v*)(HtW + ((hb + 4 * 32) ^ swz)) = pkrtz4(d4[0], d4[1], d4[2], d4[3]);
  };

  auto vtile = [&](int v, int rbase, bool full) {
    const int j0 = v * 16;
    f4 C[5];
    __builtin_amdgcn_s_setprio(1);
    #pragma unroll
    for (int c = 0; c < 5; ++c) {
      h8 bf = *(const h8*)(HtW + ((rbase + c * 32) ^ swz));
      C[c] = __builtin_amdgcn_mfma_f32_16x16x32_f16(wfrag, bf, zf, 0, 0, 0);
    }
    __builtin_amdgcn_s_setprio(0);
    // One-div rewrite: sum log10(1+rn_i/D_i) = log10(prod T_i / prod D_i),
    // T=D+rn; gated lanes contribute 1 to both products.
    // m3 gate via algebra: t1 = fmax(sGP,0)^2 -> sGP<=0 => T==D => factor 1.
    float topP = 1.f, botP = 1.f, denP = 1.f;
    const f2 z2 = {0.f, 0.f};
    if (full) {
      // gate-free path: all rows/cols in bounds; only data gate (m1/m2).
      #pragma unroll
      for (int pr2 = 0; pr2 < 2; ++pr2) {
        f2 mu1 = {C[0][2 * pr2], C[0][2 * pr2 + 1]};
        f2 mu2 = {C[1][2 * pr2], C[1][2 * pr2 + 1]};
        f2 m2c = {C[2][2 * pr2], C[2][2 * pr2 + 1]};
        f2 m3c = {C[3][2 * pr2], C[3][2 * pr2 + 1]};
        f2 m4c = {C[4][2 * pr2], C[4][2 * pr2 + 1]};
        f2 sGT = __builtin_elementwise_max(m2c - mu1 * mu1, z2);
        f2 sP  = __builtin_elementwise_max(m3c - mu2 * mu2, z2);
        f2 sGPc= __builtin_elementwise_max(m4c - mu1 * mu2, z2);
        f2 A   = sGT + EPSF;
        f2 t1  = sGPc * sGPc;
        f2 D   = A * __builtin_elementwise_fma(sP + 2.f, A, -t1);
        f2 T   = D + t1 * sGT;
        f2 dn2 = __builtin_elementwise_fma(sGT, (f2){0.5f, 0.5f}, (f2){1.f, 1.f});
        f2 mn  = __builtin_elementwise_min(sGT, sP);
        denP *= dn2[0] * dn2[1];
        #pragma unroll
        for (int e = 0; e < 2; ++e) {
          const bool valid = mn[e] >= EPSF;
          topP *= valid ? T[e] : 1.f;
          botP *= valid ? D[e] : 1.f;
        }
      }
    } else {
      #pragma unroll
      for (int pr2 = 0; pr2 < 2; ++pr2) {
        f2 mu1 = {C[0][2 * pr2], C[0][2 * pr2 + 1]};
        f2 mu2 = {C[1][2 * pr2], C[1][2 * pr2 + 1]};
        f2 m2c = {C[2][2 * pr2], C[2][2 * pr2 + 1]};
        f2 m3c = {C[3][2 * pr2], C[3][2 * pr2 + 1]};
        f2 m4c = {C[4][2 * pr2], C[4][2 * pr2 + 1]};
        f2 sGT = __builtin_elementwise_max(m2c - mu1 * mu1, z2);
        f2 sP  = __builtin_elementwise_max(m3c - mu2 * mu2, z2);
        f2 sGPc= __builtin_elementwise_max(m4c - mu1 * mu2, z2);
        f2 A   = sGT + EPSF;
        f2 t1  = sGPc * sGPc;
        f2 D   = A * __builtin_elementwise_fma(sP + 2.f, A, -t1);
        f2 T   = D + t1 * sGT;
        f2 dn2 = __builtin_elementwise_fma(sGT, (f2){0.5f, 0.5f}, (f2){1.f, 1.f});
        f2 mn  = __builtin_elementwise_min(sGT, sP);
        #pragma unroll
        for (int e = 0; e < 2; ++e) {
          const int orow = j0 + quad * 4 + pr2 * 2 + e;
          const bool inb = (orow < OVc) && colv;
          const bool valid = inb && (mn[e] >= EPSF);
          topP *= valid ? T[e] : 1.f;
          botP *= valid ? D[e] : 1.f;
          denP *= inb ? dn2[e] : 1.f;
        }
      }
    }
    numAcc += __log10f(__fdividef(topP, botP));
    denAcc += __log10f(denP);
  };

  // software pipeline, pair-unrolled: slots/parities are literals.
  htile(0, hb0);
  int v = 0;
  #pragma unroll 1
  for (; v + 1 < TIL; v += 2) {
    htile(v + 1, hb1);   // slot 1
    vtile(v, vb0, v < nFull);
    htile(v + 2, hb0);   // slot 0
    vtile(v + 1, vb1, (v + 1) < nFull);
  }
  if constexpr (TIL & 1) {       // s5/s3 tail (TIL=5)
    htile(TIL, hb1);     // t=TIL, slot 1
    vtile(TIL - 1, vb0, (TIL - 1) < nFull);
  }
}

// grid: 3840 blocks = 384 bc x 2 chunks x 5 bands, all identical type
__global__ __launch_bounds__(256, 4) void vif_fat_kernel(
    const float* __restrict__ recons, const float* __restrict__ xim,
    const float* __restrict__ Wl, float* __restrict__ ws,
    float* __restrict__ out)
{
  extern __shared__ hf lds[];
  hf* Ar = lds;
  hf* Ap = lds + APOFF;
  float* sred = (float*)(lds + SREDO);

  const int b     = blockIdx.x;
  const int band  = b % 5;
  const int rest  = b / 5;
  const int chunk = rest & 1;
  const int bc    = rest >> 1;
  const int img   = bc / 3;
  const int tid   = threadIdx.x;
  const int lane  = tid & 63;
  const int ln    = lane & 15;
  const int quad  = lane >> 4;
  const int wave  = tid >> 6;
  const int r0s   = chunk ? 58 : 0;          // first staged row

  hf* HtW = lds + HT0 + wave * HTWSZ;        // private per-wave Ht ring

  // Hoisted ring-slot bases (job/scale-invariant, 4 scalars only).
  const int qh   = quad >> 1;
  const int hq8  = 8 * (quad & 1);
  const int hb0  = ln * 160 + quad * 4;             // H slot 0
  const int hb1  = hb0 + 16;                        // H slot 1
  const int vb0  = ln * 160 + qh * 16 + hq8;        // V parity 0
  const int vb1  = ln * 160 + (qh ^ 1) * 16 + hq8;  // V parity 1

  const float* rb = recons + bc * HW;
  const float* pb = xim + bc * HW;
  const float* wb = Wl + (bc % 3) * HW;

  // ---- Stage 77x64 f16 strip (XOR-swizzled) + fused dot ----
  float dotAcc = 0.f;
  #pragma unroll
  for (int i = 0; i < 3; ++i) {
    const int it = tid + i * 256;
    if (it < RSTG * 8) {
      const int row = it >> 3;
      const int c8  = it & 7;
      const int grow = r0s + row;
      int gcol = band * 48 + c8 * 8;
      if (gcol > Wimg - 8) gcol = Wimg - 8;    // finite clamp (halo cols only)
      const int idx = grow * Wimg + gcol;
      fvec4 r0 = *(const fvec4*)(rb + idx);
      fvec4 r1 = *(const fvec4*)(rb + idx + 4);
      fvec4 p0 = *(const fvec4*)(pb + idx);
      fvec4 p1 = *(const fvec4*)(pb + idx + 4);
      h2 a0 = pkrtz(r0[0], r0[1]), a1 = pkrtz(r0[2], r0[3]);
      h2 a2 = pkrtz(r1[0], r1[1]), a3 = pkrtz(r1[2], r1[3]);
      h2 b0 = pkrtz(p0[0], p0[1]), b1 = pkrtz(p0[2], p0[3]);
      h2 b2 = pkrtz(p1[0], p1[1]), b3 = pkrtz(p1[2], p1[3]);
      const int wo = (row * ASTR + c8 * 8) ^ ((row & 7) << 3);
      *(h8*)(Ar + wo) =
          (h8){a0[0], a0[1], a1[0], a1[1], a2[0], a2[1], a3[0], a3[1]};
      *(h8*)(Ap + wo) =
          (h8){b0[0], b0[1], b1[0], b1[1], b2[0], b2[1], b3[0], b3[1]};
      const bool rowOwned = chunk ? (grow >= 68) : (grow < 68);
      if (c8 < 6 && rowOwned) {                // owned cols never clamped
        fvec4 w0 = *(const fvec4*)(wb + idx);
        fvec4 w1 = *(const fvec4*)(wb + idx + 4);
        dotAcc += (p0[0]-r0[0])*w0[0] + (p0[1]-r0[1])*w0[1]
                + (p0[2]-r0[2])*w0[2] + (p0[3]-r0[3])*w0[3]
                + (p1[0]-r1[0])*w1[0] + (p1[1]-r1[1])*w1[1]
                + (p1[2]-r1[2])*w1[2] + (p1[3]-r1[3])*w1[3];
      }
    }
  }
  __syncthreads();                            // the ONLY staging barrier

  // ---- 12 (scale,ct) jobs, 3 per wave, barrier-free ----
  // job = wave + jj*4; scale = job/3, ct = job%3.
  // jj loop MUST stay rolled: unrolling would re-create 12 instances.
  float numAcc = 0.f, denAcc = 0.f;
  #pragma unroll 1
  for (int jj = 0; jj < 3; ++jj) {
    const int job  = wave + jj * 4;
    const int sidx = job / 3;
    const int ct   = job - sidx * 3;
    switch (sidx) {
      case 0:  job_col<17>(ct, chunk, band, Ar, Ap, HtW, ln, quad,
                           hb0, hb1, vb0, vb1, numAcc, denAcc); break;
      case 1:  job_col< 9>(ct, chunk, band, Ar, Ap, HtW, ln, quad,
                           hb0, hb1, vb0, vb1, numAcc, denAcc); break;
      case 2:  job_col< 5>(ct, chunk, band, Ar, Ap, HtW, ln, quad,
                           hb0, hb1, vb0, vb1, numAcc, denAcc); break;
      default: job_col< 3>(ct, chunk, band, Ar, Ap, HtW, ln, quad,
                           hb0, hb1, vb0, vb1, numAcc, denAcc); break;
    }
  }

  // ---- block reduction (num, den, dot) ----
  #pragma unroll
  for (int off = 32; off > 0; off >>= 1) {
    numAcc += __shfl_down(numAcc, off);
    denAcc += __shfl_down(denAcc, off);
    dotAcc += __shfl_down(dotAcc, off);
  }
  __syncthreads();
  if (lane == 0) {
    sred[wave] = numAcc; sred[4 + wave] = denAcc; sred[8 + wave] = dotAcc;
  }
  __syncthreads();
  if (tid == 0) {
    atomicAdd(&ws[bc],        sred[0] + sred[1] + sred[2] + sred[3]);
    atomicAdd(&ws[384 + bc],  sred[4] + sred[5] + sred[6] + sred[7]);
    atomicAdd(&ws[768 + img], sred[8] + sred[9] + sred[10] + sred[11]);
    // Cheap release: wait for our own atomic RMWs to be performed at the
    // device coherence point. NO buffer_wbl2/buffer_inv (the R15 killer).
    asm volatile("s_waitcnt vmcnt(0)" ::: "memory");
    unsigned old = atomicAdd((unsigned*)(ws + 896), 1u);
    sred[0] = (old == TOTB - 1) ? 1.f : 0.f;
  }
  __syncthreads();
  if (sred[0] == 0.f) return;                 // not the last block

  // ---- folded finalize: only the dynamically-last block runs this ----
  asm volatile("" ::: "memory");
  float* s1 = (float*)lds;                    // reuse staged LDS
  float* s2 = s1 + 128;
  if (tid < 128) {
    float d = aload(ws + 768 + tid);
    float psq = d * d;
    float vimg = 0.f;
    #pragma unroll
    for (int c = 0; c < 3; ++c) {
      const int bcx = tid * 3 + c;
      vimg += aload(ws + bcx) / aload(ws + 384 + bcx);
    }
    float rl = 1.f - vimg * (1.f / 3.f);
    s1[tid] = psq; s2[tid] = rl;
  }
  __syncthreads();
  for (int off = 64; off > 0; off >>= 1) {
    if (tid < off) { s1[tid] += s1[tid + off]; s2[tid] += s2[tid + off]; }
    __syncthreads();
  }
  if (tid == 0) {
    float pred = s1[0] * (1.f / 128.f);
    float rec  = s2[0] * (1.f / 128.f);
    out[0] = pred + rec;
    out[1] = rec;
    out[2] = pred;
  }
}

extern "C" void kernel_launch(void* const* d_in, const int* in_sizes, int n_in,
                              void* d_out, int out_size, void* d_ws, size_t ws_size,
                              hipStream_t stream) {
  const float* recons = (const float*)d_in[0];
  const float* x      = (const float*)d_in[1];
  const float* Wl     = (const float*)d_in[2];
  float* ws  = (float*)d_ws;
  float* out = (float*)d_out;

  // zero accumulators + done-counter (897 floats; rounded up)
  hipMemsetAsync(d_ws, 0, 904 * sizeof(float), stream);

  vif_fat_kernel<<<TOTB, 256, LDSB, stream>>>(recons, x, Wl, ws, out);
}